// Round 7
// baseline (251.065 us; speedup 1.0000x reference)
//
#include <hip/hip_runtime.h>
#include <hip/hip_bf16.h>
#include <math.h>

typedef __hip_bfloat16 bf16;
typedef __attribute__((ext_vector_type(8))) short short8;
typedef __attribute__((ext_vector_type(4))) float f32x4;

#define GLD16(gp, lp)                                                          \
    __builtin_amdgcn_global_load_lds(                                          \
        (const __attribute__((address_space(1))) unsigned int*)(gp),           \
        (__attribute__((address_space(3))) unsigned int*)(lp), 16, 0, 0)

// ---------------- conversion kernels ----------------

__global__ __launch_bounds__(256) void cvt_x(const float* __restrict__ in,
                                             bf16* __restrict__ out) {
    long base = ((long)blockIdx.x * 256 + threadIdx.x) * 8;
    const float4* p = (const float4*)(in + base);
    float4 a = p[0], b = p[1];
    union { bf16 h[8]; short8 v; } o;
    o.h[0] = __float2bfloat16(a.x); o.h[1] = __float2bfloat16(a.y);
    o.h[2] = __float2bfloat16(a.z); o.h[3] = __float2bfloat16(a.w);
    o.h[4] = __float2bfloat16(b.x); o.h[5] = __float2bfloat16(b.y);
    o.h[6] = __float2bfloat16(b.z); o.h[7] = __float2bfloat16(b.w);
    *(short8*)(out + base) = o.v;
}

// W [1024(k)][1024(n)] fp32 -> WT [1024(n)][1024(k)] bf16, stacked [3072][1024]
__global__ __launch_bounds__(256) void cvt_w_t(const float* __restrict__ Wq,
                                               const float* __restrict__ Wk,
                                               const float* __restrict__ Wv,
                                               bf16* __restrict__ WT) {
    const float* W = blockIdx.z == 0 ? Wq : (blockIdx.z == 1 ? Wk : Wv);
    bf16* T = WT + (long)blockIdx.z * 1024 * 1024;
    __shared__ float t[32][33];
    int n0 = blockIdx.x * 32, k0 = blockIdx.y * 32;
    int tx = threadIdx.x, ty = threadIdx.y;  // block (32,8)
    #pragma unroll
    for (int i = 0; i < 4; ++i)
        t[ty * 4 + i][tx] = W[(long)(k0 + ty * 4 + i) * 1024 + n0 + tx];
    __syncthreads();
    #pragma unroll
    for (int i = 0; i < 4; ++i)
        T[(long)(n0 + ty * 4 + i) * 1024 + k0 + tx] =
            __float2bfloat16(t[tx][ty * 4 + i]);
}

// ------------- unified GEMM: 128x128 tile, BK=64, single-buffer -------------
// C = A * B^T, A,B row-major [rows][K]. 32 MFMA + 8 GLD16 per barrier-pair
// (2x the MFMA-per-barrier of BK=32 -> amortizes the m233 drain stall).
// LDS row = 128B = 32 banks -> 16-way conflict unless swizzled: phys 16B
// chunk p of row r holds logical chunk p^(r&7) (involution; pre-swizzled
// global source keeps global_load_lds dest linear; read XORs the same).
// MODE 1: fused QKV epilogue (Q bf16 / K bf16 / V transposed bf16)
// MODE 0: scores tri-tiles -> E=exp(s/32) bf16 causal + fp32 rowsum atomics
// MODE 2: PV heavy-first -> fp32 out / rowsum; Keff=(tm+1)*128
template <int MODE>
__global__ __launch_bounds__(256) void gemm_bt(
    const bf16* __restrict__ A, const bf16* __restrict__ B,
    void* __restrict__ C0, void* __restrict__ C1, void* __restrict__ C2,
    float* __restrict__ RS, int lda, int ldb, float alpha, long az, long bz) {
    int tm, tn, bi = 0;
    if (MODE == 1) {
        tn = blockIdx.x; tm = blockIdx.y;
    } else if (MODE == 0) {
        int t = blockIdx.x % 136;
        bi = blockIdx.x / 136;
        int i = (int)((sqrtf(8.f * t + 1.f) - 1.f) * 0.5f);
        while ((i + 1) * (i + 2) / 2 <= t) ++i;
        while (i * (i + 1) / 2 > t) --i;
        tm = i; tn = t - i * (i + 1) / 2;
    } else {  // PV heavy-first
        tm = 15 - (int)(blockIdx.x >> 5);
        int r = blockIdx.x & 31;
        tn = r & 7; bi = r >> 3;
    }
    const int nk = (MODE == 2) ? 2 * (tm + 1) : 16;  // K-steps of 64
    A += (long)bi * az;
    B += (long)bi * bz;

    const int m0 = tm * 128, n0 = tn * 128;
    __shared__ bf16 As[128 * 64];
    __shared__ bf16 Bs[128 * 64];

    const int tid = threadIdx.x;
    const int wave = tid >> 6, lane = tid & 63;
    const int wr = wave >> 1, wc = wave & 1;  // 2x2 waves, 64x64 each
    const int lrow = lane & 15, kg = lane >> 4;

    f32x4 acc[4][4];
    #pragma unroll
    for (int i = 0; i < 4; ++i)
        #pragma unroll
        for (int j = 0; j < 4; ++j) acc[i][j] = (f32x4){0.f, 0.f, 0.f, 0.f};

    // staging: per GLD16 call, thread t fills phys chunk (t&7) of row (t>>3)
    // of a 32-row block; source column pre-swizzled by the chunk involution.
    const int srow = tid >> 3;                      // 0..31
    const int scol = (((tid & 7) ^ (srow & 7)) << 3);  // elems
    const bf16* ap = A + (long)(m0 + srow) * lda + scol;
    const bf16* bp = B + (long)(n0 + srow) * ldb + scol;
    char* asb = (char*)As + tid * 16;
    char* bsb = (char*)Bs + tid * 16;

    for (int t = 0; t < nk; ++t) {
        const int k0 = t << 6;
        GLD16(ap + k0, asb);
        GLD16(ap + 32L * lda + k0, asb + 4096);
        GLD16(ap + 64L * lda + k0, asb + 8192);
        GLD16(ap + 96L * lda + k0, asb + 12288);
        GLD16(bp + k0, bsb);
        GLD16(bp + 32L * ldb + k0, bsb + 4096);
        GLD16(bp + 64L * ldb + k0, bsb + 8192);
        GLD16(bp + 96L * ldb + k0, bsb + 12288);
        __syncthreads();
        #pragma unroll
        for (int kk = 0; kk < 2; ++kk) {
            short8 af[4], bfr[4];
            #pragma unroll
            for (int mi = 0; mi < 4; ++mi) {
                const int rr = wr * 64 + mi * 16 + lrow;
                const int ch = ((kk << 2) | kg) ^ (rr & 7);
                af[mi] = *(const short8*)(&As[rr * 64 + (ch << 3)]);
            }
            #pragma unroll
            for (int ni = 0; ni < 4; ++ni) {
                const int rr = wc * 64 + ni * 16 + lrow;
                const int ch = ((kk << 2) | kg) ^ (rr & 7);
                bfr[ni] = *(const short8*)(&Bs[rr * 64 + (ch << 3)]);
            }
            #pragma unroll
            for (int mi = 0; mi < 4; ++mi)
                #pragma unroll
                for (int ni = 0; ni < 4; ++ni)
                    acc[mi][ni] = __builtin_amdgcn_mfma_f32_16x16x32_bf16(
                        af[mi], bfr[ni], acc[mi][ni], 0, 0, 0);
        }
        __syncthreads();
    }

    // C/D layout: col = lane&15, row = (lane>>4)*4 + j
    const int rb = wr * 64 + (lane >> 4) * 4;
    const int cb = wc * 64 + (lane & 15);
    if (MODE == 0) {
        bf16* E = (bf16*)C0 + (long)bi * 4194304;
        float* rsb = RS + bi * 2048;
        #pragma unroll
        for (int mi = 0; mi < 4; ++mi)
            #pragma unroll
            for (int j = 0; j < 4; ++j) {
                const int gq = m0 + rb + mi * 16 + j;
                float rp = 0.f;
                #pragma unroll
                for (int ni = 0; ni < 4; ++ni) {
                    const int gk = n0 + cb + ni * 16;
                    float e = (gk <= gq) ? __expf(acc[mi][ni][j] * alpha) : 0.f;
                    E[(long)gq * 2048 + gk] = __float2bfloat16(e);
                    rp += e;
                }
                #pragma unroll
                for (int o = 1; o < 16; o <<= 1) rp += __shfl_xor(rp, o);
                if ((lane & 15) == 0) atomicAdd(rsb + gq, rp);
            }
    } else if (MODE == 2) {
        float* Cf = (float*)C0 + (long)bi * 2097152;
        const float* rsb = RS + bi * 2048;
        #pragma unroll
        for (int mi = 0; mi < 4; ++mi)
            #pragma unroll
            for (int j = 0; j < 4; ++j) {
                const int gq = m0 + rb + mi * 16 + j;
                const float inv = 1.f / rsb[gq];
                #pragma unroll
                for (int ni = 0; ni < 4; ++ni)
                    Cf[(long)gq * 1024 + (n0 + cb + ni * 16)] =
                        acc[mi][ni][j] * inv;
            }
    } else {
        const int sel = n0 >> 10;  // 0=Q, 1=K, 2=V
        const int nb = n0 & 1023;
        if (sel < 2) {
            bf16* Cb = sel ? (bf16*)C1 : (bf16*)C0;
            #pragma unroll
            for (int mi = 0; mi < 4; ++mi)
                #pragma unroll
                for (int ni = 0; ni < 4; ++ni)
                    #pragma unroll
                    for (int j = 0; j < 4; ++j)
                        Cb[(long)(m0 + rb + mi * 16 + j) * 1024 + (nb + cb + ni * 16)] =
                            __float2bfloat16(acc[mi][ni][j]);
        } else {
            // V^T: [4 batches][1024 cols][2048 seq]; 4 rows -> one 8B store
            bf16* T = (bf16*)C2;
            #pragma unroll
            for (int mi = 0; mi < 4; ++mi)
                #pragma unroll
                for (int ni = 0; ni < 4; ++ni) {
                    int gm = m0 + rb + mi * 16;
                    int col = nb + cb + ni * 16;
                    int b = gm >> 11, mm = gm & 2047;
                    union { bf16 h[4]; ushort4 v; } o;
                    #pragma unroll
                    for (int j = 0; j < 4; ++j)
                        o.h[j] = __float2bfloat16(acc[mi][ni][j]);
                    *(ushort4*)(T + (long)b * 2097152 + (long)col * 2048 + mm) = o.v;
                }
        }
    }
}

// ---------------- launch ----------------
extern "C" void kernel_launch(void* const* d_in, const int* in_sizes, int n_in,
                              void* d_out, int out_size, void* d_ws,
                              size_t ws_size, hipStream_t stream) {
    const float* x = (const float*)d_in[0];
    const float* Wq = (const float*)d_in[1];
    const float* Wk = (const float*)d_in[2];
    const float* Wv = (const float*)d_in[3];
    float* out = (float*)d_out;

    char* ws = (char*)d_ws;
    bf16* xb = (bf16*)ws;                     // 8192x1024 bf16
    bf16* wt = (bf16*)(ws + 16777216);        // 3072x1024 bf16
    bf16* Qb = (bf16*)(ws + 23068672);        // 8192x1024 bf16
    bf16* Kb = (bf16*)(ws + 39845888);        // 8192x1024 bf16
    bf16* VT = (bf16*)(ws + 56623104);        // 4x 1024x2048 bf16
    bf16* E  = (bf16*)(ws + 73400320);        // 4x 2048x2048 bf16
    float* rs = (float*)(ws + 106954752);     // 4x 2048 fp32
    if (ws_size < 106987520) return;

    cvt_x<<<4096, 256, 0, stream>>>(x, xb);
    cvt_w_t<<<dim3(32, 32, 3), dim3(32, 8), 0, stream>>>(Wq, Wk, Wv, wt);
    hipMemsetAsync(rs, 0, 4 * 2048 * sizeof(float), stream);
    // fused QKV: M=8192, N=3072, K=1024 -> 1536 blocks
    gemm_bt<1><<<dim3(24, 64), 256, 0, stream>>>(
        xb, wt, Qb, Kb, VT, nullptr, 1024, 1024, 1.f, 0, 0);
    // E = exp(QK^T/32) causal + rowsums: 4 x 136 = 544 blocks
    gemm_bt<0><<<544, 256, 0, stream>>>(
        Qb, Kb, E, nullptr, nullptr, rs, 1024, 1024, 0.03125f, 2097152,
        2097152);
    // O = (E V)/rowsum: 512 blocks, heavy-first causal Keff
    gemm_bt<2><<<512, 256, 0, stream>>>(
        E, VT, out, nullptr, nullptr, rs, 2048, 2048, 1.f, 4194304, 2097152);
}

// Round 8
// 229.422 us; speedup vs baseline: 1.0943x; 1.0943x over previous
//
#include <hip/hip_runtime.h>
#include <hip/hip_bf16.h>
#include <math.h>

typedef __hip_bfloat16 bf16;
typedef __attribute__((ext_vector_type(8))) short short8;
typedef __attribute__((ext_vector_type(4))) float f32x4;

#define GLD16(gp, lp)                                                          \
    __builtin_amdgcn_global_load_lds(                                          \
        (const __attribute__((address_space(1))) unsigned int*)(gp),           \
        (__attribute__((address_space(3))) unsigned int*)(lp), 16, 0, 0)

// ---------------- conversion kernels ----------------

__global__ __launch_bounds__(256) void cvt_x(const float* __restrict__ in,
                                             bf16* __restrict__ out) {
    long base = ((long)blockIdx.x * 256 + threadIdx.x) * 8;
    const float4* p = (const float4*)(in + base);
    float4 a = p[0], b = p[1];
    union { bf16 h[8]; short8 v; } o;
    o.h[0] = __float2bfloat16(a.x); o.h[1] = __float2bfloat16(a.y);
    o.h[2] = __float2bfloat16(a.z); o.h[3] = __float2bfloat16(a.w);
    o.h[4] = __float2bfloat16(b.x); o.h[5] = __float2bfloat16(b.y);
    o.h[6] = __float2bfloat16(b.z); o.h[7] = __float2bfloat16(b.w);
    *(short8*)(out + base) = o.v;
}

// W [1024(k)][1024(n)] fp32 -> WT [1024(n)][1024(k)] bf16, stacked [3072][1024]
__global__ __launch_bounds__(256) void cvt_w_t(const float* __restrict__ Wq,
                                               const float* __restrict__ Wk,
                                               const float* __restrict__ Wv,
                                               bf16* __restrict__ WT) {
    const float* W = blockIdx.z == 0 ? Wq : (blockIdx.z == 1 ? Wk : Wv);
    bf16* T = WT + (long)blockIdx.z * 1024 * 1024;
    __shared__ float t[32][33];
    int n0 = blockIdx.x * 32, k0 = blockIdx.y * 32;
    int tx = threadIdx.x, ty = threadIdx.y;  // block (32,8)
    #pragma unroll
    for (int i = 0; i < 4; ++i)
        t[ty * 4 + i][tx] = W[(long)(k0 + ty * 4 + i) * 1024 + n0 + tx];
    __syncthreads();
    #pragma unroll
    for (int i = 0; i < 4; ++i)
        T[(long)(n0 + ty * 4 + i) * 1024 + k0 + tx] =
            __float2bfloat16(t[tx][ty * 4 + i]);
}

// ============ deep-pipelined GEMM: C = A*B^T, counted-vmcnt schedule ========
// BM = MF*32 (MF=8 -> 256, MF=4 -> 128), BN = 256, BK = 32.
// 512 threads = 8 waves as 2(M) x 4(N); per-wave tile (MF*16) x 64.
// LDS: 3 K-tile buffers (A: BM*32, B: 256*32 bf16 each) -> pipeline depth 2:
//   compute tile t  |  tile t+1 resident  |  tile t+2 staging in flight.
// One raw s_barrier per K-tile; s_waitcnt vmcnt(TL) counted (TL = loads/tile
// = BM/128 + 2), NEVER 0 in steady state -> stage latency hidden under MFMA.
// Safety: reads of buf X are lgkm-drained before the barrier; writes to the
// recycled buf are issued after it. sched_barrier(0) pins the schedule.
// LDS swizzle (R3-verified, 0 conflicts): phys 16B chunk p of row r holds
// logical chunk p ^ ((r>>1)&3); source pre-swizzled, reads XOR the same.
// MODE 1: fused QKV epilogue  MODE 0: E=exp(s/32)+rowsum  MODE 2: PV/rowsum
template <int MODE, int MF>
__global__ __launch_bounds__(512, 2) void gemm8p(
    const bf16* __restrict__ A, const bf16* __restrict__ B,
    void* __restrict__ C0, void* __restrict__ C1, void* __restrict__ C2,
    float* __restrict__ RS, int lda, int ldb, float alpha, long az, long bz) {
    int tm, tn, bi = 0;
    if (MODE == 1) {
        tn = blockIdx.x; tm = blockIdx.y;
    } else if (MODE == 0) {
        int t = blockIdx.x % 36;
        bi = blockIdx.x / 36;
        int i = (int)((sqrtf(8.f * t + 1.f) - 1.f) * 0.5f);
        while ((i + 1) * (i + 2) / 2 <= t) ++i;
        while (i * (i + 1) / 2 > t) --i;
        tm = i; tn = t - i * (i + 1) / 2;
    } else {  // PV heavy-first: 16 tm x (4 tn x 4 bi)
        tm = 15 - (int)(blockIdx.x >> 4);
        int r = blockIdx.x & 15;
        tn = r & 3; bi = r >> 2;
    }
    const int BM = MF * 32;
    const int nk = (MODE == 2) ? 4 * (tm + 1) : 32;  // K-steps of 32
    A += (long)bi * az;
    B += (long)bi * bz;
    const int m0 = tm * BM, n0 = tn * 256;

    const int ABUF = MF * 1024;                  // A-buffer elems (BM*32)
    __shared__ bf16 lds[3 * (MF * 1024 + 8192)];
    bf16* Ab[3] = {lds, lds + ABUF, lds + 2 * ABUF};
    bf16* Bb[3] = {lds + 3 * ABUF, lds + 3 * ABUF + 8192, lds + 3 * ABUF + 16384};

    const int tid = threadIdx.x;
    const int wave = tid >> 6, lane = tid & 63;
    const int wr = wave >> 2, wc = wave & 3;     // 2 x 4 waves
    const int lrow = lane & 15, kg = lane >> 4;

    f32x4 acc[MF][4];
    #pragma unroll
    for (int i = 0; i < MF; ++i)
        #pragma unroll
        for (int j = 0; j < 4; ++j) acc[i][j] = (f32x4){0.f, 0.f, 0.f, 0.f};

    // staging: 4 threads/row, thread fills phys chunk (tid&3) of row tid>>2;
    // global source column pre-swizzled by the chunk involution.
    const int srow = tid >> 2;                         // 0..127
    const int scol = ((((srow >> 1) & 3) ^ (tid & 3)) << 3);
    const bf16* ap = A + (long)(m0 + srow) * lda + scol;
    const bf16* bp = B + (long)(n0 + srow) * ldb + scol;

    #define STAGE_A(buf, kof)                                                  \
        { char* d = (char*)(buf) + tid * 16;                                   \
          GLD16(ap + (kof), d);                                                \
          if (MF == 8) GLD16(ap + 128L * lda + (kof), d + 8192); }
    #define STAGE_B(buf, kof)                                                  \
        { char* d = (char*)(buf) + tid * 16;                                   \
          GLD16(bp + (kof), d);                                                \
          GLD16(bp + 128L * ldb + (kof), d + 8192); }

    auto LDF = [&](const bf16* buf, int rr) {
        return *(const short8*)(buf + rr * 32 + ((kg ^ ((rr >> 1) & 3)) << 3));
    };

    // prologue: tile0 -> buf0, tile1 -> buf1 (issue order = vmcnt order)
    STAGE_A(Ab[0], 0); STAGE_B(Bb[0], 0);
    STAGE_A(Ab[1], 32); STAGE_B(Bb[1], 32);

    bf16 *acu = Ab[0], *anx = Ab[1], *ast = Ab[2];
    bf16 *bcu = Bb[0], *bnx = Bb[1], *bst = Bb[2];

    for (int t = 0; t < nk; ++t) {
        // counted wait: tile t landed; tile t+1's TL loads stay in flight
        if (t + 1 < nk) {
            if (MF == 8) asm volatile("s_waitcnt vmcnt(4)" ::: "memory");
            else         asm volatile("s_waitcnt vmcnt(3)" ::: "memory");
        } else {
            asm volatile("s_waitcnt vmcnt(0)" ::: "memory");
        }
        __builtin_amdgcn_s_barrier();
        __builtin_amdgcn_sched_barrier(0);

        const int kst = (t + 2) << 5;
        const bool stg = (t + 2) < nk;
        if (stg) { STAGE_A(ast, kst); if (MF == 4) STAGE_B(bst, kst); }

        // phase 0: B frags + first 4 A frags, first MFMA quadrant(s)
        short8 bfr[4], af[4];
        #pragma unroll
        for (int ni = 0; ni < 4; ++ni)
            bfr[ni] = LDF(bcu, wc * 64 + ni * 16 + lrow);
        #pragma unroll
        for (int mi = 0; mi < 4 && mi < MF; ++mi)
            af[mi] = LDF(acu, wr * (MF * 16) + mi * 16 + lrow);
        __builtin_amdgcn_s_setprio(1);
        #pragma unroll
        for (int mi = 0; mi < 4 && mi < MF; ++mi)
            #pragma unroll
            for (int ni = 0; ni < 4; ++ni)
                acc[mi][ni] = __builtin_amdgcn_mfma_f32_16x16x32_bf16(
                    af[mi], bfr[ni], acc[mi][ni], 0, 0, 0);
        __builtin_amdgcn_s_setprio(0);

        if (MF == 8) {  // phase 1: stage B, A frags 4..7, second quadrants
            if (stg) STAGE_B(bst, kst);
            short8 af2[4];
            #pragma unroll
            for (int mi = 0; mi < 4; ++mi)
                af2[mi] = LDF(acu, wr * 128 + 64 + mi * 16 + lrow);
            __builtin_amdgcn_s_setprio(1);
            #pragma unroll
            for (int mi = 0; mi < 4; ++mi)
                #pragma unroll
                for (int ni = 0; ni < 4; ++ni)
                    acc[(MF == 8 ? mi + 4 : mi)][ni] =
                        __builtin_amdgcn_mfma_f32_16x16x32_bf16(
                            af2[mi], bfr[ni], acc[(MF == 8 ? mi + 4 : mi)][ni],
                            0, 0, 0);
            __builtin_amdgcn_s_setprio(0);
        }
        // rotate buffers: (cur,next,stage) <- (next,stage,cur)
        bf16* ta = acu; acu = anx; anx = ast; ast = ta;
        bf16* tb = bcu; bcu = bnx; bnx = bst; bst = tb;
    }
    #undef STAGE_A
    #undef STAGE_B

    // C/D layout: col = lane&15, row = (lane>>4)*4 + j   [m89-verified]
    const int rb = wr * (MF * 16) + (lane >> 4) * 4;
    const int cb = wc * 64 + (lane & 15);
    if (MODE == 0) {
        bf16* E = (bf16*)C0 + (long)bi * 4194304;
        float* rsb = RS + bi * 2048;
        #pragma unroll
        for (int mi = 0; mi < MF; ++mi)
            #pragma unroll
            for (int j = 0; j < 4; ++j) {
                const int gq = m0 + rb + mi * 16 + j;
                float rp = 0.f;
                #pragma unroll
                for (int ni = 0; ni < 4; ++ni) {
                    const int gk = n0 + cb + ni * 16;
                    float e = (gk <= gq) ? __expf(acc[mi][ni][j] * alpha) : 0.f;
                    E[(long)gq * 2048 + gk] = __float2bfloat16(e);
                    rp += e;
                }
                #pragma unroll
                for (int o = 1; o < 16; o <<= 1) rp += __shfl_xor(rp, o);
                if ((lane & 15) == 0) atomicAdd(rsb + gq, rp);
            }
    } else if (MODE == 2) {
        float* Cf = (float*)C0 + (long)bi * 2097152;
        const float* rsb = RS + bi * 2048;
        #pragma unroll
        for (int mi = 0; mi < MF; ++mi)
            #pragma unroll
            for (int j = 0; j < 4; ++j) {
                const int gq = m0 + rb + mi * 16 + j;
                const float inv = 1.f / rsb[gq];
                #pragma unroll
                for (int ni = 0; ni < 4; ++ni)
                    Cf[(long)gq * 1024 + (n0 + cb + ni * 16)] =
                        acc[mi][ni][j] * inv;
            }
    } else {
        const int sel = n0 >> 10;  // 0=Q, 1=K, 2=V (uniform per block)
        const int nb = n0 & 1023;
        if (sel < 2) {
            bf16* Cb = sel ? (bf16*)C1 : (bf16*)C0;
            #pragma unroll
            for (int mi = 0; mi < MF; ++mi)
                #pragma unroll
                for (int ni = 0; ni < 4; ++ni)
                    #pragma unroll
                    for (int j = 0; j < 4; ++j)
                        Cb[(long)(m0 + rb + mi * 16 + j) * 1024 + (nb + cb + ni * 16)] =
                            __float2bfloat16(acc[mi][ni][j]);
        } else {
            // V^T: [4 batches][1024 cols][2048 seq]; 4 rows -> one 8B store
            bf16* T = (bf16*)C2;
            #pragma unroll
            for (int mi = 0; mi < MF; ++mi)
                #pragma unroll
                for (int ni = 0; ni < 4; ++ni) {
                    int gm = m0 + rb + mi * 16;
                    int col = nb + cb + ni * 16;
                    int b = gm >> 11, mm = gm & 2047;
                    union { bf16 h[4]; ushort4 v; } o;
                    #pragma unroll
                    for (int j = 0; j < 4; ++j)
                        o.h[j] = __float2bfloat16(acc[mi][ni][j]);
                    *(ushort4*)(T + (long)b * 2097152 + (long)col * 2048 + mm) = o.v;
                }
        }
    }
}

// ---------------- launch ----------------
extern "C" void kernel_launch(void* const* d_in, const int* in_sizes, int n_in,
                              void* d_out, int out_size, void* d_ws,
                              size_t ws_size, hipStream_t stream) {
    const float* x = (const float*)d_in[0];
    const float* Wq = (const float*)d_in[1];
    const float* Wk = (const float*)d_in[2];
    const float* Wv = (const float*)d_in[3];
    float* out = (float*)d_out;

    char* ws = (char*)d_ws;
    bf16* xb = (bf16*)ws;                     // 8192x1024 bf16
    bf16* wt = (bf16*)(ws + 16777216);        // 3072x1024 bf16
    bf16* Qb = (bf16*)(ws + 23068672);        // 8192x1024 bf16
    bf16* Kb = (bf16*)(ws + 39845888);        // 8192x1024 bf16
    bf16* VT = (bf16*)(ws + 56623104);        // 4x 1024x2048 bf16
    bf16* E  = (bf16*)(ws + 73400320);        // 4x 2048x2048 bf16
    float* rs = (float*)(ws + 106954752);     // 4x 2048 fp32
    if (ws_size < 106987520) return;

    cvt_x<<<4096, 256, 0, stream>>>(x, xb);
    cvt_w_t<<<dim3(32, 32, 3), dim3(32, 8), 0, stream>>>(Wq, Wk, Wv, wt);
    hipMemsetAsync(rs, 0, 4 * 2048 * sizeof(float), stream);
    // fused QKV: 256^2 tiles, M=8192 N=3072 -> 12 x 32 = 384 blocks
    gemm8p<1, 8><<<dim3(12, 32), 512, 0, stream>>>(
        xb, wt, Qb, Kb, VT, nullptr, 1024, 1024, 1.f, 0, 0);
    // E = exp(QK^T/32) causal + rowsums: 256^2 tri tiles, 4 x 36 = 144 blocks
    gemm8p<0, 8><<<144, 512, 0, stream>>>(
        Qb, Kb, E, nullptr, nullptr, rs, 1024, 1024, 0.03125f, 2097152,
        2097152);
    // O = (E V)/rowsum: 128x256 tiles, heavy-first, 16 x 16 = 256 blocks
    gemm8p<2, 4><<<256, 512, 0, stream>>>(
        E, VT, out, nullptr, nullptr, rs, 2048, 2048, 1.f, 4194304, 2097152);
}

// Round 10
// 225.825 us; speedup vs baseline: 1.1118x; 1.0159x over previous
//
#include <hip/hip_runtime.h>
#include <hip/hip_bf16.h>
#include <math.h>

typedef __hip_bfloat16 bf16;
typedef __attribute__((ext_vector_type(8))) short short8;
typedef __attribute__((ext_vector_type(4))) float f32x4;

#define GLD16(gp, lp)                                                          \
    __builtin_amdgcn_global_load_lds(                                          \
        (const __attribute__((address_space(1))) unsigned int*)(gp),           \
        (__attribute__((address_space(3))) unsigned int*)(lp), 16, 0, 0)

// ---------------- conversion kernels ----------------

__global__ __launch_bounds__(256) void cvt_x(const float* __restrict__ in,
                                             bf16* __restrict__ out) {
    long base = ((long)blockIdx.x * 256 + threadIdx.x) * 8;
    const float4* p = (const float4*)(in + base);
    float4 a = p[0], b = p[1];
    union { bf16 h[8]; short8 v; } o;
    o.h[0] = __float2bfloat16(a.x); o.h[1] = __float2bfloat16(a.y);
    o.h[2] = __float2bfloat16(a.z); o.h[3] = __float2bfloat16(a.w);
    o.h[4] = __float2bfloat16(b.x); o.h[5] = __float2bfloat16(b.y);
    o.h[6] = __float2bfloat16(b.z); o.h[7] = __float2bfloat16(b.w);
    *(short8*)(out + base) = o.v;
}

// W [1024(k)][1024(n)] fp32 -> WT [1024(n)][1024(k)] bf16, stacked [3072][1024]
__global__ __launch_bounds__(256) void cvt_w_t(const float* __restrict__ Wq,
                                               const float* __restrict__ Wk,
                                               const float* __restrict__ Wv,
                                               bf16* __restrict__ WT) {
    const float* W = blockIdx.z == 0 ? Wq : (blockIdx.z == 1 ? Wk : Wv);
    bf16* T = WT + (long)blockIdx.z * 1024 * 1024;
    __shared__ float t[32][33];
    int n0 = blockIdx.x * 32, k0 = blockIdx.y * 32;
    int tx = threadIdx.x, ty = threadIdx.y;  // block (32,8)
    #pragma unroll
    for (int i = 0; i < 4; ++i)
        t[ty * 4 + i][tx] = W[(long)(k0 + ty * 4 + i) * 1024 + n0 + tx];
    __syncthreads();
    #pragma unroll
    for (int i = 0; i < 4; ++i)
        T[(long)(n0 + ty * 4 + i) * 1024 + k0 + tx] =
            __float2bfloat16(t[tx][ty * 4 + i]);
}

// ====== deep-pipelined GEMM: C = A*B^T, 3-buffer counted-vmcnt schedule =====
// BM = MF*64 (MF=4 -> 256, MF=2 -> 128), BN = 128, BK = 64.
// 512 threads = 8 waves as 4(M) x 2(N); wave tile (MF*16) x 64;
// acc[MF][4], B-frags register-persistent per K-tile.
// 3 LDS buffers (A BM*64 + B 128*64 bf16): compute t | t+1 resident | t+2
// staging.  s_waitcnt vmcnt(6|4) counted - never 0 mid-loop; ONE s_barrier
// per K-tile + sched_barrier(0) pin (race-required: vmcnt only covers the
// wave's own loads; the barrier publishes all waves' staged portions).
// Swizzle (R7-verified 0 conflicts): phys 16B chunk p of row r holds logical
// chunk p^(r&7); read XOR term = lane&7 (constant -> folds to immediates);
// global source pre-swizzled so global_load_lds dest stays linear.
// MODE 1: fused QKV epilogue   MODE 0: E=exp(s/32)+rowsum   MODE 2: PV
// MODE 2 runs TWO complementary jobs (tm, 15-tm): 34 K-tiles every block.
template <int MODE, int MF>
__global__ __launch_bounds__(512, 2) void gemmdp(
    const bf16* __restrict__ A, const bf16* __restrict__ B,
    void* __restrict__ C0, void* __restrict__ C1, void* __restrict__ C2,
    float* __restrict__ RS, int lda, int ldb, float alpha, long az, long bz) {
    constexpr int BM = MF * 64;
    constexpr int S = MF * 4096 + 8192;  // elems per buffer (A + B)
    __shared__ bf16 lds[3 * S];

    const int tid = threadIdx.x;
    const int wave = tid >> 6, lane = tid & 63;
    const int wr = wave >> 1, wc = wave & 1;  // 4M x 2N waves
    const int lrow = lane & 15, kg = lane >> 4;
    const int s7 = lane & 7;

    int tn, bi, tm0;
    if (MODE == 1) {
        tn = blockIdx.x; tm0 = blockIdx.y; bi = 0;
    } else if (MODE == 0) {
        int t = blockIdx.x % 72; bi = blockIdx.x / 72;
        // cum(tm) = tm*(tm+1); count(tm) = 2(tm+1); 8 q-tiles x 16 k-tiles
        int m = (int)((sqrtf(4.f * t + 1.f) - 1.f) * 0.5f);
        while ((m + 1) * (m + 2) <= t) ++m;
        while (m * (m + 1) > t) --m;
        tm0 = m; tn = t - m * (m + 1);
    } else {
        int r = blockIdx.x & 31;
        tn = r & 7; bi = r >> 3; tm0 = blockIdx.x >> 5;  // pair (tm0, 15-tm0)
    }
    const bf16* Abase = A + (long)bi * az;
    const bf16* Bbase = B + (long)bi * bz;
    const int srow = tid >> 3;                        // 0..63
    const int scol = (((tid & 7) ^ (srow & 7)) << 3); // pre-swizzled source
    const int n0 = tn * 128;

    const int NJOB = (MODE == 2) ? 2 : 1;
    for (int job = 0; job < NJOB; ++job) {
        const int tm = (MODE == 2 && job) ? 15 - tm0 : tm0;
        const int m0 = tm * BM;
        const int nk = (MODE == 2) ? 2 * (tm + 1) : 16;

        const bf16* ap = Abase + (long)(m0 + srow) * lda + scol;
        const bf16* bp = Bbase + (long)(n0 + srow) * ldb + scol;

        f32x4 acc[MF][4];
        #pragma unroll
        for (int i = 0; i < MF; ++i)
            #pragma unroll
            for (int j = 0; j < 4; ++j) acc[i][j] = (f32x4){0.f, 0.f, 0.f, 0.f};

        #define STG(bb, k0)                                                    \
            { char* d = (char*)(bb) + tid * 16;                                \
              _Pragma("unroll")                                                \
              for (int q = 0; q < MF; ++q)                                     \
                  GLD16(ap + (long)(64 * q) * lda + (k0), d + q * 8192);       \
              GLD16(bp + (k0), d + MF * 8192);                                 \
              GLD16(bp + 64L * ldb + (k0), d + MF * 8192 + 8192); }

        STG(lds, 0);
        STG(lds + S, 64);
        bf16 *cur = lds, *nxt = lds + S, *stg = lds + 2 * S;

        for (int t = 0; t < nk; ++t) {
            if (t + 1 < nk) {
                if (MF == 4) asm volatile("s_waitcnt vmcnt(6)" ::: "memory");
                else         asm volatile("s_waitcnt vmcnt(4)" ::: "memory");
            } else {
                asm volatile("s_waitcnt vmcnt(0)" ::: "memory");
            }
            __builtin_amdgcn_s_barrier();
            __builtin_amdgcn_sched_barrier(0);  // nothing crosses the publish
            if (t + 2 < nk) STG(stg, (t + 2) << 6);

            const bf16* ab = cur;
            const bf16* bb = cur + MF * 4096;
            short8 bq0[4], bq1[4];
            #pragma unroll
            for (int ni = 0; ni < 4; ++ni) {
                const int rr = wc * 64 + ni * 16 + lrow;
                bq0[ni] = *(const short8*)(bb + rr * 64 + ((kg ^ s7) << 3));
                bq1[ni] = *(const short8*)(bb + rr * 64 + (((4 | kg) ^ s7) << 3));
            }
            #pragma unroll
            for (int mi = 0; mi < MF; ++mi) {
                const int rr = wr * (MF * 16) + mi * 16 + lrow;
                short8 a0 = *(const short8*)(ab + rr * 64 + ((kg ^ s7) << 3));
                short8 a1 = *(const short8*)(ab + rr * 64 + (((4 | kg) ^ s7) << 3));
                __builtin_amdgcn_s_setprio(1);
                #pragma unroll
                for (int ni = 0; ni < 4; ++ni)
                    acc[mi][ni] = __builtin_amdgcn_mfma_f32_16x16x32_bf16(
                        a0, bq0[ni], acc[mi][ni], 0, 0, 0);
                #pragma unroll
                for (int ni = 0; ni < 4; ++ni)
                    acc[mi][ni] = __builtin_amdgcn_mfma_f32_16x16x32_bf16(
                        a1, bq1[ni], acc[mi][ni], 0, 0, 0);
                __builtin_amdgcn_s_setprio(0);
            }
            bf16* tp = cur; cur = nxt; nxt = stg; stg = tp;
        }
        #undef STG

        // C/D layout: col = lane&15, row = (lane>>4)*4 + j   [m89-verified]
        const int rb = wr * (MF * 16) + (lane >> 4) * 4;
        const int cb = wc * 64 + lrow;
        if (MODE == 0) {
            bf16* E = (bf16*)C0 + (long)bi * 4194304;
            float* rsb = RS + bi * 2048;
            #pragma unroll
            for (int mi = 0; mi < MF; ++mi)
                #pragma unroll
                for (int j = 0; j < 4; ++j) {
                    const int gq = m0 + rb + mi * 16 + j;
                    float rp = 0.f;
                    #pragma unroll
                    for (int ni = 0; ni < 4; ++ni) {
                        const int gk = n0 + cb + ni * 16;
                        float e = (gk <= gq) ? __expf(acc[mi][ni][j] * alpha) : 0.f;
                        E[(long)gq * 2048 + gk] = __float2bfloat16(e);
                        rp += e;
                    }
                    #pragma unroll
                    for (int o = 1; o < 16; o <<= 1) rp += __shfl_xor(rp, o);
                    if (lrow == 0) atomicAdd(rsb + gq, rp);
                }
        } else if (MODE == 2) {
            float* Cf = (float*)C0 + (long)bi * 2097152;
            const float* rsb = RS + bi * 2048;
            #pragma unroll
            for (int mi = 0; mi < MF; ++mi)
                #pragma unroll
                for (int j = 0; j < 4; ++j) {
                    const int gq = m0 + rb + mi * 16 + j;
                    const float inv = 1.f / rsb[gq];
                    #pragma unroll
                    for (int ni = 0; ni < 4; ++ni)
                        Cf[(long)gq * 1024 + (n0 + cb + ni * 16)] =
                            acc[mi][ni][j] * inv;
                }
        } else {
            const int sel = n0 >> 10;  // 0=Q, 1=K, 2=V (uniform per block)
            const int nb = n0 & 1023;
            if (sel < 2) {
                bf16* Cb = sel ? (bf16*)C1 : (bf16*)C0;
                #pragma unroll
                for (int mi = 0; mi < MF; ++mi)
                    #pragma unroll
                    for (int ni = 0; ni < 4; ++ni)
                        #pragma unroll
                        for (int j = 0; j < 4; ++j)
                            Cb[(long)(m0 + rb + mi * 16 + j) * 1024 +
                               (nb + cb + ni * 16)] =
                                __float2bfloat16(acc[mi][ni][j]);
            } else {
                // V^T: [4 batches][1024 cols][2048 seq]; 4 rows -> 8B store
                bf16* T = (bf16*)C2;
                #pragma unroll
                for (int mi = 0; mi < MF; ++mi)
                    #pragma unroll
                    for (int ni = 0; ni < 4; ++ni) {
                        int gm = m0 + rb + mi * 16;
                        int col = nb + cb + ni * 16;
                        int b = gm >> 11, mm = gm & 2047;
                        union { bf16 h[4]; ushort4 v; } o;
                        #pragma unroll
                        for (int j = 0; j < 4; ++j)
                            o.h[j] = __float2bfloat16(acc[mi][ni][j]);
                        *(ushort4*)(T + (long)b * 2097152 + (long)col * 2048 + mm) =
                            o.v;
                    }
            }
        }
        if (MODE == 2 && job == 0)
            __builtin_amdgcn_s_barrier();  // job0 LDS reads done before job1 stages
    }
}

// ---------------- launch ----------------
extern "C" void kernel_launch(void* const* d_in, const int* in_sizes, int n_in,
                              void* d_out, int out_size, void* d_ws,
                              size_t ws_size, hipStream_t stream) {
    const float* x = (const float*)d_in[0];
    const float* Wq = (const float*)d_in[1];
    const float* Wk = (const float*)d_in[2];
    const float* Wv = (const float*)d_in[3];
    float* out = (float*)d_out;

    char* ws = (char*)d_ws;
    bf16* xb = (bf16*)ws;                     // 8192x1024 bf16
    bf16* wt = (bf16*)(ws + 16777216);        // 3072x1024 bf16
    bf16* Qb = (bf16*)(ws + 23068672);        // 8192x1024 bf16
    bf16* Kb = (bf16*)(ws + 39845888);        // 8192x1024 bf16
    bf16* VT = (bf16*)(ws + 56623104);        // 4x 1024x2048 bf16
    bf16* E  = (bf16*)(ws + 73400320);        // 4x 2048x2048 bf16
    float* rs = (float*)(ws + 106954752);     // 4x 2048 fp32
    if (ws_size < 106987520) return;

    cvt_x<<<4096, 256, 0, stream>>>(x, xb);
    cvt_w_t<<<dim3(32, 32, 3), dim3(32, 8), 0, stream>>>(Wq, Wk, Wv, wt);
    hipMemsetAsync(rs, 0, 4 * 2048 * sizeof(float), stream);
    // fused QKV: 256x128 tiles -> 24 x 32 = 768 blocks = exactly 3 waves
    gemmdp<1, 4><<<dim3(24, 32), 512, 0, stream>>>(
        xb, wt, Qb, Kb, VT, nullptr, 1024, 1024, 1.f, 0, 0);
    // E = exp(QK^T/32) causal + rowsums: 256(q)x128(k) tri, 4 x 72 = 288
    gemmdp<0, 4><<<288, 512, 0, stream>>>(
        Qb, Kb, E, nullptr, nullptr, rs, 1024, 1024, 0.03125f, 2097152,
        2097152);
    // O = (E V)/rowsum: 128x128 tiles, paired q-tiles (tm,15-tm) -> 256
    // blocks = exactly 1 wave, 34 K-tiles each (perfect balance)
    gemmdp<2, 2><<<256, 512, 0, stream>>>(
        E, VT, out, nullptr, nullptr, rs, 2048, 2048, 1.f, 4194304, 2097152);
}